// Round 12
// baseline (147.146 us; speedup 1.0000x reference)
//
#include <hip/hip_runtime.h>
#include <hip/hip_bf16.h>
#include <math.h>

#define BB 4
#define CC 192
#define HH 56
#define WW 56
#define HWW 3136

typedef __attribute__((ext_vector_type(8))) short short8;
typedef __attribute__((ext_vector_type(4))) float f32x4;

__device__ __forceinline__ unsigned short f2b(float f) {
    __hip_bfloat16 h = __float2bfloat16(f);
    return __builtin_bit_cast(unsigned short, h);
}
__device__ __forceinline__ float b2f(unsigned short u) {
    unsigned int x = ((unsigned int)u) << 16;
    return __builtin_bit_cast(float, x);
}
__device__ __forceinline__ void fma4(float4& a, float w, const float4& x) {
    a.x += w * x.x; a.y += w * x.y; a.z += w * x.z; a.w += w * x.w;
}

// ---------------------------------------------------------------------------
// Kernel 1 (fused independent work, reads only inputs):
//   blocks [0,2352):    transpose x (B,C,H,W) -> xt (B,HW,C) f32
//   blocks [2352,2640): W' = [C1;C2] -> split bf16 (N=384, K=192)
//   blocks [2640,4432): scores (pair symmetry), reading x DIRECTLY
// sp layout: [half][b][pix][32] f32 (27 slots used).
// ---------------------------------------------------------------------------
__global__ __launch_bounds__(256) void k_front(const float* __restrict__ x,
                                               const float* __restrict__ cw,
                                               float* __restrict__ xt,
                                               unsigned short* __restrict__ cwh,
                                               unsigned short* __restrict__ cwl,
                                               float* __restrict__ sp) {
    __shared__ float S[2800];        // 11.2 KB union
    int tid = threadIdx.x, bid = blockIdx.x;

    if (bid < 2352) {                // ---- transpose ----
        float (*tile)[33] = (float (*)[33])S;
        int b = bid / 588, rem = bid % 588;
        int by = rem / 98, bx = rem % 98;
        int tx = tid & 31, ty = tid >> 5;
        int p0 = bx * 32, c0 = by * 32;
#pragma unroll
        for (int i = 0; i < 4; i++) {
            int c = c0 + ty + 8 * i;
            tile[ty + 8 * i][tx] = x[(b * CC + c) * HWW + p0 + tx];
        }
        __syncthreads();
#pragma unroll
        for (int i = 0; i < 4; i++) {
            int p = p0 + ty + 8 * i;
            xt[(size_t)(b * HWW + p) * CC + c0 + tx] = tile[tx][ty + 8 * i];
        }
        return;
    }
    if (bid < 2640) {                // ---- conv_w split: W' = [C1;C2] ----
        int i = (bid - 2352) * 256 + tid;    // 288*256 = 73728 = 384*192
        if (i < 384 * 192) {
            int n = i / 192, k = i % 192;
            float v = (n < 192) ? cw[n * 384 + k] : cw[(n - 192) * 384 + 192 + k];
            unsigned short hi = f2b(v);
            cwh[i] = hi;
            cwl[i] = f2b(v - b2f(hi));
        }
        return;
    }
    // ---- scores (from x directly; R10-verified code) ----
    int vb = bid - 2640;             // 0..1791
    bool isH = vb < 896;
    int lid = isH ? vb : vb - 896;
    int half = lid & 1;
    int rp = (lid >> 1) & 1;         // residue pair: classes {2rp, 2rp+1}
    int cb2 = lid >> 2;              // 0..223
    int b = cb2 / 56, l0 = cb2 % 56; // column w (H) or row h (W)
    int r0 = rp * 2;
    const float SC = 0.62040705607059197f;   // sqrt(2/sqrt(27))

    if (isH) {
        for (int idx = tid; idx < 28 * 96; idx += 256) {
            int t2 = idx / 96, c = idx % 96;
            int pi = (r0 + t2 / 14) + 4 * (t2 % 14);
            float v = x[(size_t)(b * CC + half * 96 + c) * HWW + pi * WW + l0];
            S[t2 * 100 + c] = v * SC;
        }
    } else {
        for (int idx = tid; idx < 96 * 14; idx += 256) {
            int c = idx / 14, k = idx % 14;
            float2 v = *(const float2*)&x[(size_t)(b * CC + half * 96 + c) * HWW +
                                          l0 * WW + r0 + 4 * k];
            S[k * 100 + c]        = v.x * SC;
            S[(14 + k) * 100 + c] = v.y * SC;
        }
    }
    __syncthreads();

    int perCls = isH ? 105 : 91;
    if (tid < 2 * perCls) {
        int cls = tid / perCls, p = tid % perCls;
        int a, bb;
        if (isH) {
            a = (int)((sqrtf((float)(8 * p + 1)) - 1.0f) * 0.5f);
            bb = p - (a * (a + 1)) / 2;
        } else {
            int ap = (int)((sqrtf((float)(8 * p + 1)) - 1.0f) * 0.5f);
            bb = p - (ap * (ap + 1)) / 2;
            a = ap + 1;
        }
        const float* pA = &S[(cls * 14 + a) * 100];
        const float* pB = &S[(cls * 14 + bb) * 100];
        float s0 = 0.f, s1 = 0.f, s2 = 0.f, s3 = 0.f;
#pragma unroll
        for (int q = 0; q < 24; q++) {
            float4 av = *(const float4*)(pA + q * 4);
            float4 bv = *(const float4*)(pB + q * 4);
            s0 += __builtin_amdgcn_rcpf(__expf(av.x * bv.x) + 1.0f);
            s1 += __builtin_amdgcn_rcpf(__expf(av.y * bv.y) + 1.0f);
            s2 += __builtin_amdgcn_rcpf(__expf(av.z * bv.z) + 1.0f);
            s3 += __builtin_amdgcn_rcpf(__expf(av.w * bv.w) + 1.0f);
        }
        float s = 96.0f - 2.0f * (s0 + s1 + s2 + s3);   // sum_c tanh
        int r = r0 + cls;
        size_t base = (size_t)(half * BB + b) * HWW;
        if (isH) {
            int i1 = a - bb;
            int h1 = r + 4 * a, h2 = r + 4 * bb;
            sp[(base + h1 * WW + l0) * 32 + i1] = s;
            if (a != bb) sp[(base + h2 * WW + l0) * 32 + (14 - i1)] = s;
        } else {
            int d = a - bb;                        // 1..13
            int w1 = r + 4 * a, w2 = r + 4 * bb;
            sp[(base + l0 * WW + w1) * 32 + 14 + (d - 1)] = s;
            sp[(base + l0 * WW + w2) * 32 + 14 + (13 - d)] = s;
        }
    }
}

// ---------------------------------------------------------------------------
// Kernel 2: split-bf16 MFMA GEMM [u|z] = W'·x^T, M-tile 112 (= 2 pixel rows),
// N-tile 64, K=192 (chunks of 64). 672 blocks = 112 m-tiles x 6 n-tiles.
// z-tiles (bn>=192) additionally compute the W-roll sum in the epilogue
// (rows are complete inside the tile) -> yW.  u-tiles store u.
// ---------------------------------------------------------------------------
__global__ __launch_bounds__(256) void k_gemm(const float* __restrict__ xt,
                                              const unsigned short* __restrict__ cwh,
                                              const unsigned short* __restrict__ cwl,
                                              const float* __restrict__ sp,
                                              float* __restrict__ u,
                                              float* __restrict__ z,
                                              float* __restrict__ yW) {
    __shared__ __align__(16) char smem[50688];
    unsigned short* Ah = (unsigned short*)smem;                 // 112x72 bf16
    unsigned short* Al = Ah + 112 * 72;
    unsigned short* Bh = Ah + 2 * 112 * 72;                     // 64x72
    unsigned short* Bl = Bh + 64 * 72;
    float* Ds  = (float*)smem;                                  // 112x68 f32
    float* WtL = (float*)(smem + 30464);                        // 13x112 f32

    int tid = threadIdx.x, lane = tid & 63, wv = tid >> 6;
    int bm = (blockIdx.x % 112) * 112;
    int bn = (blockIdx.x / 112) * 64;
    bool is_z = bn >= 192;

    f32x4 acc[7] = {{0,0,0,0},{0,0,0,0},{0,0,0,0},{0,0,0,0},
                    {0,0,0,0},{0,0,0,0},{0,0,0,0}};

    for (int kc = 0; kc < 192; kc += 64) {
        for (int idx = tid; idx < 112 * 8; idx += 256) {       // A: 112 rows x 64k
            int m = idx >> 3, kq = idx & 7;
            const float* s = xt + (size_t)(bm + m) * CC + kc + kq * 8;
            float4 v0 = *(const float4*)s;
            float4 v1 = *(const float4*)(s + 4);
            float vv[8] = {v0.x, v0.y, v0.z, v0.w, v1.x, v1.y, v1.z, v1.w};
            unsigned short hi[8], lo[8];
#pragma unroll
            for (int e = 0; e < 8; e++) {
                hi[e] = f2b(vv[e]);
                lo[e] = f2b(vv[e] - b2f(hi[e]));
            }
            *(short8*)&Ah[m * 72 + kq * 8] = *(short8*)hi;
            *(short8*)&Al[m * 72 + kq * 8] = *(short8*)lo;
        }
        {
            int idx = tid;                                      // B: 64 rows x 64k
            int n = idx >> 3, kq = idx & 7;                     // 512 = 256x2
            size_t bo = (size_t)(bn + n) * 192 + kc + kq * 8;
            *(short8*)&Bh[n * 72 + kq * 8] = *(const short8*)(cwh + bo);
            *(short8*)&Bl[n * 72 + kq * 8] = *(const short8*)(cwl + bo);
            idx = tid + 256; n = idx >> 3; kq = idx & 7;
            bo = (size_t)(bn + n) * 192 + kc + kq * 8;
            *(short8*)&Bh[n * 72 + kq * 8] = *(const short8*)(cwh + bo);
            *(short8*)&Bl[n * 72 + kq * 8] = *(const short8*)(cwl + bo);
        }
        __syncthreads();
        int k8 = lane >> 4;
        int col = lane & 15;
#pragma unroll
        for (int ks = 0; ks < 64; ks += 32) {
            int koff = ks + k8 * 8;
            short8 bfh = *(const short8*)&Bh[(wv * 16 + col) * 72 + koff];
            short8 bfl = *(const short8*)&Bl[(wv * 16 + col) * 72 + koff];
#pragma unroll
            for (int fm = 0; fm < 7; fm++) {
                short8 afh = *(const short8*)&Ah[(fm * 16 + col) * 72 + koff];
                short8 afl = *(const short8*)&Al[(fm * 16 + col) * 72 + koff];
                acc[fm] = __builtin_amdgcn_mfma_f32_16x16x32_bf16(afh, bfh, acc[fm], 0, 0, 0);
                acc[fm] = __builtin_amdgcn_mfma_f32_16x16x32_bf16(afl, bfh, acc[fm], 0, 0, 0);
                acc[fm] = __builtin_amdgcn_mfma_f32_16x16x32_bf16(afh, bfl, acc[fm], 0, 0, 0);
            }
        }
        __syncthreads();
    }

    int b = bm / HWW, p0 = bm % HWW;

    // D -> LDS transpose: Ds[m][n-within-64], stride 68
    {
        int col = lane & 15, rowq = lane >> 4;
#pragma unroll
        for (int fm = 0; fm < 7; fm++)
#pragma unroll
            for (int rg = 0; rg < 4; rg++)
                Ds[(fm * 16 + rowq * 4 + rg) * 68 + wv * 16 + col] = acc[fm][rg];
    }
    // z-tiles: softmax -> W-weights for the 112 pixels
    if (is_z && tid < 112) {
        const float4* q0 = (const float4*)&sp[((size_t)(0 * BB + b) * HWW + p0 + tid) * 32];
        const float4* q1 = (const float4*)&sp[((size_t)(1 * BB + b) * HWW + p0 + tid) * 32];
        float sc[28];
#pragma unroll
        for (int j = 0; j < 7; j++) {
            float4 a = q0[j], v = q1[j];
            sc[4 * j + 0] = a.x + v.x; sc[4 * j + 1] = a.y + v.y;
            sc[4 * j + 2] = a.z + v.z; sc[4 * j + 3] = a.w + v.w;
        }
        float mx = -1e30f;
#pragma unroll
        for (int s = 0; s < 27; s++) mx = fmaxf(mx, sc[s]);
        float sum = 0.f;
#pragma unroll
        for (int s = 0; s < 27; s++) { sc[s] = __expf(sc[s] - mx); sum += sc[s]; }
        float inv = __builtin_amdgcn_rcpf(sum);
#pragma unroll
        for (int j = 0; j < 13; j++) WtL[j * 112 + tid] = sc[14 + j] * inv;
    }
    __syncthreads();

    // store u or z (coalesced pixel-major)
    {
        int c4 = tid & 15, m0 = tid >> 4;
        float* dst = is_z ? z : u;
        int cc = is_z ? (bn - 192) : bn;
#pragma unroll
        for (int p = 0; p < 7; p++) {
            int m = m0 + p * 16;
            float4 v = *(float4*)&Ds[m * 68 + c4 * 4];
            *(float4*)&dst[(size_t)(bm + m) * CC + cc + c4 * 4] = v;
        }
    }
    // z-tiles: W-roll sum within the 2 rows -> yW
    if (is_z && tid < 128) {
        int row2 = tid >> 6;          // 0,1: which pixel-row
        int r = (tid >> 4) & 3;       // residue class
        int q = tid & 15;             // channel quad (of 64)
        int pr = row2 * 56;
        int cz = bn - 192;
        float4 in[14];
#pragma unroll
        for (int t = 0; t < 14; t++)
            in[t] = *(const float4*)&Ds[(pr + r + 4 * t) * 68 + q * 4];
        float4 acw[14] = {};
#pragma unroll
        for (int j = 0; j < 13; j++)
#pragma unroll
            for (int a = 0; a < 14; a++)
                fma4(acw[a], WtL[j * 112 + pr + r + 4 * a], in[(a - j - 1 + 14) % 14]);
#pragma unroll
        for (int a = 0; a < 14; a++) {
            int m = pr + r + 4 * a;
            *(float4*)&yW[(size_t)(bm + m) * CC + cz + q * 4] = acw[a];
        }
    }
}

// ---------------------------------------------------------------------------
// Kernel 3: per-column finale: y = GELU(BN(u + yW + Hsum(z))) -> (B,C,H,W)
// 224 blocks (b, column l0), 192 threads.
// ---------------------------------------------------------------------------
__global__ __launch_bounds__(192) void k_fin(const float* __restrict__ u,
                                             const float* __restrict__ z,
                                             const float* __restrict__ yW,
                                             const float* __restrict__ sp,
                                             const float* __restrict__ cb,
                                             const float* __restrict__ gma,
                                             const float* __restrict__ bta,
                                             const float* __restrict__ mea,
                                             const float* __restrict__ var,
                                             float* __restrict__ y) {
    __shared__ float Wt[14 * 56];
    int bid = blockIdx.x, tid = threadIdx.x;
    int b = bid / 56, l0 = bid % 56;

    if (tid < 56) {
        int pix = tid * WW + l0;
        const float4* q0 = (const float4*)&sp[((size_t)(0 * BB + b) * HWW + pix) * 32];
        const float4* q1 = (const float4*)&sp[((size_t)(1 * BB + b) * HWW + pix) * 32];
        float sc[28];
#pragma unroll
        for (int j = 0; j < 7; j++) {
            float4 a = q0[j], v = q1[j];
            sc[4 * j + 0] = a.x + v.x; sc[4 * j + 1] = a.y + v.y;
            sc[4 * j + 2] = a.z + v.z; sc[4 * j + 3] = a.w + v.w;
        }
        float mx = -1e30f;
#pragma unroll
        for (int s = 0; s < 27; s++) mx = fmaxf(mx, sc[s]);
        float sum = 0.f;
#pragma unroll
        for (int s = 0; s < 27; s++) { sc[s] = __expf(sc[s] - mx); sum += sc[s]; }
        float inv = __builtin_amdgcn_rcpf(sum);
#pragma unroll
        for (int i = 0; i < 14; i++) Wt[i * 56 + tid] = sc[i] * inv;
    }
    __syncthreads();
    {
        int r = tid & 3, q = tid >> 2;
        float4 in[14];
#pragma unroll
        for (int t = 0; t < 14; t++) {
            int pix = (r + 4 * t) * WW + l0;
            in[t] = *(const float4*)(z + (size_t)(b * HWW + pix) * CC + q * 4);
        }
        float4 acc[14];
#pragma unroll
        for (int a = 0; a < 14; a++) {
            int pix = (r + 4 * a) * WW + l0;
            size_t off = (size_t)(b * HWW + pix) * CC + q * 4;
            float4 uu = *(const float4*)(u + off);
            float4 ww = *(const float4*)(yW + off);
            acc[a].x = uu.x + ww.x; acc[a].y = uu.y + ww.y;
            acc[a].z = uu.z + ww.z; acc[a].w = uu.w + ww.w;
        }
#pragma unroll
        for (int i = 0; i < 14; i++)
#pragma unroll
            for (int a = 0; a < 14; a++)
                fma4(acc[a], Wt[i * 56 + (r + 4 * a)], in[(a - i + 14) % 14]);

        float4 bias4 = *(const float4*)&cb[q * 4];
        float4 g4 = *(const float4*)&gma[q * 4];
        float4 bt4 = *(const float4*)&bta[q * 4];
        float4 me4 = *(const float4*)&mea[q * 4];
        float4 va4 = *(const float4*)&var[q * 4];
        float inv0 = g4.x * rsqrtf(va4.x + 1e-5f);
        float inv1 = g4.y * rsqrtf(va4.y + 1e-5f);
        float inv2 = g4.z * rsqrtf(va4.z + 1e-5f);
        float inv3 = g4.w * rsqrtf(va4.w + 1e-5f);
#pragma unroll
        for (int a = 0; a < 14; a++) {
            int h = r + 4 * a;
            float4 t = acc[a];
            t.x = (t.x + bias4.x - me4.x) * inv0 + bt4.x;
            t.y = (t.y + bias4.y - me4.y) * inv1 + bt4.y;
            t.z = (t.z + bias4.z - me4.z) * inv2 + bt4.z;
            t.w = (t.w + bias4.w - me4.w) * inv3 + bt4.w;
            t.x = 0.5f * t.x * (1.0f + erff(t.x * 0.70710678118654752f));
            t.y = 0.5f * t.y * (1.0f + erff(t.y * 0.70710678118654752f));
            t.z = 0.5f * t.z * (1.0f + erff(t.z * 0.70710678118654752f));
            t.w = 0.5f * t.w * (1.0f + erff(t.w * 0.70710678118654752f));
            size_t yb = (size_t)(b * CC + q * 4) * HWW + h * WW + l0;
            y[yb] = t.x;
            y[yb + HWW] = t.y;
            y[yb + 2 * HWW] = t.z;
            y[yb + 3 * HWW] = t.w;
        }
    }
}

// ---------------------------------------------------------------------------
extern "C" void kernel_launch(void* const* d_in, const int* in_sizes, int n_in,
                              void* d_out, int out_size, void* d_ws, size_t ws_size,
                              hipStream_t stream) {
    const float* x   = (const float*)d_in[0];
    const float* cw  = (const float*)d_in[1];
    const float* cb  = (const float*)d_in[2];
    const float* gma = (const float*)d_in[3];
    const float* bta = (const float*)d_in[4];
    const float* mea = (const float*)d_in[5];
    const float* var = (const float*)d_in[6];
    float* out = (float*)d_out;

    float* ws = (float*)d_ws;
    float*          xt  = ws;                                   // 2,408,448
    float*          sp  = ws + 2408448;                         //   802,816
    float*          u   = ws + 3211264;                         // 2,408,448
    float*          z   = ws + 5619712;                         // 2,408,448
    float*          yW  = ws + 8028160;                         // 2,408,448
    unsigned short* cwh = (unsigned short*)(ws + 10436608);     //    73,728 us
    unsigned short* cwl = (unsigned short*)(ws + 10473472);

    k_front<<<4432, 256, 0, stream>>>(x, cw, xt, cwh, cwl, sp);
    k_gemm<<<672, 256, 0, stream>>>(xt, cwh, cwl, sp, u, z, yW);
    k_fin<<<224, 192, 0, stream>>>(u, z, yW, sp, cb, gma, bta, mea, var, out);
}

// Round 13
// 135.266 us; speedup vs baseline: 1.0878x; 1.0878x over previous
//
#include <hip/hip_runtime.h>
#include <hip/hip_bf16.h>
#include <math.h>

#define BB 4
#define CC 192
#define HH 56
#define WW 56
#define HWW 3136

typedef __attribute__((ext_vector_type(8))) short short8;
typedef __attribute__((ext_vector_type(4))) float f32x4;

__device__ __forceinline__ unsigned short f2b(float f) {
    __hip_bfloat16 h = __float2bfloat16(f);
    return __builtin_bit_cast(unsigned short, h);
}
__device__ __forceinline__ float b2f(unsigned short u) {
    unsigned int x = ((unsigned int)u) << 16;
    return __builtin_bit_cast(float, x);
}
__device__ __forceinline__ void fma4(float4& a, float w, const float4& x) {
    a.x += w * x.x; a.y += w * x.y; a.z += w * x.z; a.w += w * x.w;
}

// ---------------------------------------------------------------------------
// Kernel 1 (R11-identical): blocks [0,2352): transpose x -> xt (B,HW,C) f32
//           blocks [2352,2640): W' = [C1;C2] -> split bf16 (N=384, K=192)
// ---------------------------------------------------------------------------
__global__ __launch_bounds__(256) void k_pre(const float* __restrict__ x,
                                             const float* __restrict__ cw,
                                             float* __restrict__ xt,
                                             unsigned short* __restrict__ cwh,
                                             unsigned short* __restrict__ cwl) {
    int tid = threadIdx.x, bid = blockIdx.x;
    if (bid < 2352) {
        __shared__ float tile[32][33];
        int b = bid / 588, rem = bid % 588;
        int by = rem / 98, bx = rem % 98;
        int tx = tid & 31, ty = tid >> 5;
        int p0 = bx * 32, c0 = by * 32;
#pragma unroll
        for (int i = 0; i < 4; i++) {
            int c = c0 + ty + 8 * i;
            tile[ty + 8 * i][tx] = x[(b * CC + c) * HWW + p0 + tx];
        }
        __syncthreads();
#pragma unroll
        for (int i = 0; i < 4; i++) {
            int p = p0 + ty + 8 * i;
            xt[(size_t)(b * HWW + p) * CC + c0 + tx] = tile[tx][ty + 8 * i];
        }
    } else {
        int i = (bid - 2352) * 256 + tid;     // 288*256 = 73728 = 384*192
        if (i < 384 * 192) {
            int n = i / 192, k = i % 192;
            float v = (n < 192) ? cw[n * 384 + k] : cw[(n - 192) * 384 + 192 + k];
            unsigned short hi = f2b(v);
            cwh[i] = hi;
            cwl[i] = f2b(v - b2f(hi));
        }
    }
}

// ---------------------------------------------------------------------------
// Kernel 2 (R11-identical): blocks [0,1792): scores -> sp [half][b][pix][32]
//   blocks [1792,2968): GEMM [u|z] = W'·x^T, M=12544, N=384, K=192, split-bf16
// ---------------------------------------------------------------------------
__global__ __launch_bounds__(256) void k_mid(const float* __restrict__ xt,
                                             const unsigned short* __restrict__ cwh,
                                             const unsigned short* __restrict__ cwl,
                                             float* __restrict__ sp,
                                             float* __restrict__ u,
                                             float* __restrict__ z) {
    __shared__ __align__(16) char smem[36864];
    int tid = threadIdx.x, bid = blockIdx.x;

    if (bid < 1792) {                 // ---------------- scores ----------------
        float* Xs = (float*)smem;     // 28 rows x 96ch (+4 pad)
        const float K2 = 0.38490017945975050f;  // 2/sqrt(27)
        bool isH = bid < 896;
        int lid = isH ? bid : bid - 896;
        int half = lid & 1;
        int rp = (lid >> 1) & 1;
        int cb2 = lid >> 2;
        int b = cb2 / 56, l0 = cb2 % 56;
        int r0 = rp * 2;

        const float* src = xt + (size_t)(b * HWW) * CC + half * 96;
        for (int idx = tid; idx < 28 * 24; idx += 256) {
            int t2 = idx / 24, cq = idx % 24;
            int pi = (r0 + t2 / 14) + 4 * (t2 % 14);
            int pix = isH ? (pi * WW + l0) : (l0 * WW + pi);
            float4 v = *(const float4*)(src + (size_t)pix * CC + cq * 4);
            *(float4*)&Xs[t2 * 100 + cq * 4] = v;
        }
        __syncthreads();

        int perCls = isH ? 105 : 91;
        if (tid < 2 * perCls) {
            int cls = tid / perCls, p = tid % perCls;
            int a, bb;
            if (isH) {
                a = (int)((sqrtf((float)(8 * p + 1)) - 1.0f) * 0.5f);
                bb = p - (a * (a + 1)) / 2;
            } else {
                int ap = (int)((sqrtf((float)(8 * p + 1)) - 1.0f) * 0.5f);
                bb = p - (ap * (ap + 1)) / 2;
                a = ap + 1;
            }
            const float* pA = &Xs[(cls * 14 + a) * 100];
            const float* pB = &Xs[(cls * 14 + bb) * 100];
            float s0 = 0.f, s1 = 0.f, s2 = 0.f, s3 = 0.f;
#pragma unroll
            for (int q = 0; q < 24; q++) {
                float4 av = *(const float4*)(pA + q * 4);
                float4 bv = *(const float4*)(pB + q * 4);
                s0 += __builtin_amdgcn_rcpf(__expf(av.x * bv.x * K2) + 1.0f);
                s1 += __builtin_amdgcn_rcpf(__expf(av.y * bv.y * K2) + 1.0f);
                s2 += __builtin_amdgcn_rcpf(__expf(av.z * bv.z * K2) + 1.0f);
                s3 += __builtin_amdgcn_rcpf(__expf(av.w * bv.w * K2) + 1.0f);
            }
            float s = 96.0f - 2.0f * (s0 + s1 + s2 + s3);   // sum_c tanh
            int r = r0 + cls;
            size_t base = (size_t)(half * BB + b) * HWW;
            if (isH) {
                int i1 = a - bb;
                int h1 = r + 4 * a, h2 = r + 4 * bb;
                sp[(base + h1 * WW + l0) * 32 + i1] = s;
                if (a != bb) sp[(base + h2 * WW + l0) * 32 + (14 - i1)] = s;
            } else {
                int d = a - bb;                        // 1..13
                int w1 = r + 4 * a, w2 = r + 4 * bb;
                sp[(base + l0 * WW + w1) * 32 + 14 + (d - 1)] = s;
                sp[(base + l0 * WW + w2) * 32 + 14 + (13 - d)] = s;
            }
        }
        return;
    }

    // ---------------- GEMM [u|z], split-bf16, tile 64x64, K=192 ----------------
    {
        unsigned short* Ah = (unsigned short*)smem;
        unsigned short* Al = Ah + 64 * 72;
        unsigned short* Bh = Ah + 2 * 64 * 72;
        unsigned short* Bl = Ah + 3 * 64 * 72;
        float* Ds = (float*)smem;
        int vb = bid - 1792;                  // 0..1175
        int bm = (vb % 196) * 64, bn = (vb / 196) * 64;
        int lane = tid & 63, wv = tid >> 6;

        f32x4 acc[4] = {{0,0,0,0},{0,0,0,0},{0,0,0,0},{0,0,0,0}};

        for (int kc = 0; kc < 3; kc++) {
#pragma unroll
            for (int r2 = 0; r2 < 2; r2++) {
                int idx = tid + r2 * 256;
                int m = idx >> 3, kq = idx & 7;
                const float* s = xt + (size_t)(bm + m) * CC + kc * 64 + kq * 8;
                float4 v0 = *(const float4*)s;
                float4 v1 = *(const float4*)(s + 4);
                float vv[8] = {v0.x, v0.y, v0.z, v0.w, v1.x, v1.y, v1.z, v1.w};
                unsigned short hi[8], lo[8];
#pragma unroll
                for (int e = 0; e < 8; e++) {
                    hi[e] = f2b(vv[e]);
                    lo[e] = f2b(vv[e] - b2f(hi[e]));
                }
                *(short8*)&Ah[m * 72 + kq * 8] = *(short8*)hi;
                *(short8*)&Al[m * 72 + kq * 8] = *(short8*)lo;
                size_t bo = (size_t)(bn + m) * 192 + kc * 64 + kq * 8;
                *(short8*)&Bh[m * 72 + kq * 8] = *(const short8*)(cwh + bo);
                *(short8*)&Bl[m * 72 + kq * 8] = *(const short8*)(cwl + bo);
            }
            __syncthreads();
            int n0 = wv * 16;
            int k8 = lane >> 4;
            int col = lane & 15;
#pragma unroll
            for (int ks = 0; ks < 64; ks += 32) {
                int koff = ks + k8 * 8;
                short8 bfh = *(const short8*)&Bh[(n0 + col) * 72 + koff];
                short8 bfl = *(const short8*)&Bl[(n0 + col) * 72 + koff];
#pragma unroll
                for (int fm = 0; fm < 4; fm++) {
                    short8 afh = *(const short8*)&Ah[(fm * 16 + col) * 72 + koff];
                    short8 afl = *(const short8*)&Al[(fm * 16 + col) * 72 + koff];
                    acc[fm] = __builtin_amdgcn_mfma_f32_16x16x32_bf16(afh, bfh, acc[fm], 0, 0, 0);
                    acc[fm] = __builtin_amdgcn_mfma_f32_16x16x32_bf16(afl, bfh, acc[fm], 0, 0, 0);
                    acc[fm] = __builtin_amdgcn_mfma_f32_16x16x32_bf16(afh, bfl, acc[fm], 0, 0, 0);
                }
            }
            __syncthreads();
        }
        {
            int col = lane & 15, rowq = lane >> 4;
#pragma unroll
            for (int fm = 0; fm < 4; fm++)
#pragma unroll
                for (int rg = 0; rg < 4; rg++)
                    Ds[(fm * 16 + rowq * 4 + rg) * 68 + wv * 16 + col] = acc[fm][rg];
        }
        __syncthreads();
        {
            int c4 = tid & 15, m0 = tid >> 4;
            int cg = bn + c4 * 4;
            float* dst = (cg < 192) ? u : z;
            int cc = (cg < 192) ? cg : cg - 192;
#pragma unroll
            for (int p = 0; p < 4; p++) {
                int m = m0 + p * 16;
                float4 v = *(float4*)&Ds[m * 68 + c4 * 4];
                *(float4*)&dst[(size_t)(bm + m) * CC + cc] = v;
            }
        }
    }
}

// ---------------------------------------------------------------------------
// Kernel 3 (merged finale): per-row block (b, h):
//   y(h,·) = GELU(BN(u(h,·) + Wsum(own z row) + Hsum(13+1 residue rows of z)))
// 224 blocks, 192 threads. One softmax yields all 27 weights.
// ---------------------------------------------------------------------------
__global__ __launch_bounds__(192) void k_fin(const float* __restrict__ u,
                                             const float* __restrict__ z,
                                             const float* __restrict__ sp,
                                             const float* __restrict__ cb,
                                             const float* __restrict__ gma,
                                             const float* __restrict__ bta,
                                             const float* __restrict__ mea,
                                             const float* __restrict__ var,
                                             float* __restrict__ y) {
    __shared__ float Wt[27 * 56];    // [s][w]
    __shared__ float Ys[56 * 196];   // [w][c]
    int bid = blockIdx.x, tid = threadIdx.x;
    int b = bid / 56, h = bid % 56;

    if (tid < 56) {
        int pix = h * WW + tid;
        const float4* q0 = (const float4*)&sp[((size_t)(0 * BB + b) * HWW + pix) * 32];
        const float4* q1 = (const float4*)&sp[((size_t)(1 * BB + b) * HWW + pix) * 32];
        float sc[28];
#pragma unroll
        for (int j = 0; j < 7; j++) {
            float4 a = q0[j], v = q1[j];
            sc[4 * j + 0] = a.x + v.x; sc[4 * j + 1] = a.y + v.y;
            sc[4 * j + 2] = a.z + v.z; sc[4 * j + 3] = a.w + v.w;
        }
        float mx = -1e30f;
#pragma unroll
        for (int s = 0; s < 27; s++) mx = fmaxf(mx, sc[s]);
        float sum = 0.f;
#pragma unroll
        for (int s = 0; s < 27; s++) { sc[s] = __expf(sc[s] - mx); sum += sc[s]; }
        float inv = __builtin_amdgcn_rcpf(sum);
#pragma unroll
        for (int s = 0; s < 27; s++) Wt[s * 56 + tid] = sc[s] * inv;
    }
    __syncthreads();
    {
        int r = tid & 3, q = tid >> 2;        // w-residue, channel quad (0..47)
        // ---- init with u + W-sum (own row) ----
        float4 inW[14];
#pragma unroll
        for (int t = 0; t < 14; t++)
            inW[t] = *(const float4*)(z + (size_t)(b * HWW + h * WW + (r + 4 * t)) * CC + q * 4);
        float4 acc[14];
#pragma unroll
        for (int a = 0; a < 14; a++)
            acc[a] = *(const float4*)(u + (size_t)(b * HWW + h * WW + (r + 4 * a)) * CC + q * 4);
#pragma unroll
        for (int j = 0; j < 13; j++)
#pragma unroll
            for (int a = 0; a < 14; a++)
                fma4(acc[a], Wt[(14 + j) * 56 + (r + 4 * a)], inW[(a - j - 1 + 14) % 14]);
        // ---- H-sum: stream the 14 residue rows (i=0 is own row = inW[·]) ----
#pragma unroll
        for (int a = 0; a < 14; a++)
            fma4(acc[a], Wt[0 * 56 + (r + 4 * a)], inW[a]);   // i=0: z(h, w)
#pragma unroll 1
        for (int i = 1; i < 14; i++) {
            int h2 = h - 4 * i; if (h2 < 0) h2 += 56;
            const float* zr = z + (size_t)(b * HWW + h2 * WW) * CC + q * 4;
#pragma unroll
            for (int a = 0; a < 14; a++) {
                float4 v = *(const float4*)(zr + (size_t)(r + 4 * a) * CC);
                fma4(acc[a], Wt[i * 56 + (r + 4 * a)], v);
            }
        }
        // ---- BN + GELU, stage to Ys[w][c] ----
        float4 bias4 = *(const float4*)&cb[q * 4];
        float4 g4 = *(const float4*)&gma[q * 4];
        float4 bt4 = *(const float4*)&bta[q * 4];
        float4 me4 = *(const float4*)&mea[q * 4];
        float4 va4 = *(const float4*)&var[q * 4];
        float inv0 = g4.x * rsqrtf(va4.x + 1e-5f);
        float inv1 = g4.y * rsqrtf(va4.y + 1e-5f);
        float inv2 = g4.z * rsqrtf(va4.z + 1e-5f);
        float inv3 = g4.w * rsqrtf(va4.w + 1e-5f);
#pragma unroll
        for (int a = 0; a < 14; a++) {
            int w = r + 4 * a;
            float4 t = acc[a];
            t.x = (t.x + bias4.x - me4.x) * inv0 + bt4.x;
            t.y = (t.y + bias4.y - me4.y) * inv1 + bt4.y;
            t.z = (t.z + bias4.z - me4.z) * inv2 + bt4.z;
            t.w = (t.w + bias4.w - me4.w) * inv3 + bt4.w;
            t.x = 0.5f * t.x * (1.0f + erff(t.x * 0.70710678118654752f));
            t.y = 0.5f * t.y * (1.0f + erff(t.y * 0.70710678118654752f));
            t.z = 0.5f * t.z * (1.0f + erff(t.z * 0.70710678118654752f));
            t.w = 0.5f * t.w * (1.0f + erff(t.w * 0.70710678118654752f));
            *(float4*)&Ys[w * 196 + q * 4] = t;
        }
    }
    __syncthreads();
    {
        int c = tid;   // 0..191
#pragma unroll
        for (int w4 = 0; w4 < 14; w4++) {
            float4 v;
            v.x = Ys[(w4 * 4 + 0) * 196 + c];
            v.y = Ys[(w4 * 4 + 1) * 196 + c];
            v.z = Ys[(w4 * 4 + 2) * 196 + c];
            v.w = Ys[(w4 * 4 + 3) * 196 + c];
            *(float4*)&y[(size_t)(b * CC + c) * HWW + h * WW + w4 * 4] = v;
        }
    }
}

// ---------------------------------------------------------------------------
extern "C" void kernel_launch(void* const* d_in, const int* in_sizes, int n_in,
                              void* d_out, int out_size, void* d_ws, size_t ws_size,
                              hipStream_t stream) {
    const float* x   = (const float*)d_in[0];
    const float* cw  = (const float*)d_in[1];
    const float* cb  = (const float*)d_in[2];
    const float* gma = (const float*)d_in[3];
    const float* bta = (const float*)d_in[4];
    const float* mea = (const float*)d_in[5];
    const float* var = (const float*)d_in[6];
    float* out = (float*)d_out;

    float* ws = (float*)d_ws;
    float*          xt  = ws;                                   // 2,408,448
    float*          sp  = ws + 2408448;                         //   802,816
    float*          u   = ws + 3211264;                         // 2,408,448
    float*          z   = ws + 5619712;                         // 2,408,448
    unsigned short* cwh = (unsigned short*)(ws + 8028160);      //    73,728 us
    unsigned short* cwl = (unsigned short*)(ws + 8065024);

    k_pre<<<2640, 256, 0, stream>>>(x, cw, xt, cwh, cwl);
    k_mid<<<2968, 256, 0, stream>>>(xt, cwh, cwl, sp, u, z);
    k_fin<<<224, 192, 0, stream>>>(u, z, sp, cb, gma, bta, mea, var, out);
}

// Round 15
// 129.671 us; speedup vs baseline: 1.1348x; 1.0431x over previous
//
#include <hip/hip_runtime.h>
#include <hip/hip_bf16.h>
#include <math.h>

#define BB 4
#define CC 192
#define HH 56
#define WW 56
#define HWW 3136

typedef __attribute__((ext_vector_type(8))) short short8;
typedef __attribute__((ext_vector_type(4))) float f32x4;

__device__ __forceinline__ unsigned short f2b(float f) {
    __hip_bfloat16 h = __float2bfloat16(f);
    return __builtin_bit_cast(unsigned short, h);
}
__device__ __forceinline__ float b2f(unsigned short u) {
    unsigned int x = ((unsigned int)u) << 16;
    return __builtin_bit_cast(float, x);
}
__device__ __forceinline__ void fma4(float4& a, float w, const float4& x) {
    a.x += w * x.x; a.y += w * x.y; a.z += w * x.z; a.w += w * x.w;
}

// ---------------------------------------------------------------------------
// Kernel 1 (R11-identical): blocks [0,2352): transpose x -> xt (B,HW,C) f32
//           blocks [2352,2640): W' = [C1;C2] -> split bf16 (N=384, K=192)
// ---------------------------------------------------------------------------
__global__ __launch_bounds__(256) void k_pre(const float* __restrict__ x,
                                             const float* __restrict__ cw,
                                             float* __restrict__ xt,
                                             unsigned short* __restrict__ cwh,
                                             unsigned short* __restrict__ cwl) {
    int tid = threadIdx.x, bid = blockIdx.x;
    if (bid < 2352) {
        __shared__ float tile[32][33];
        int b = bid / 588, rem = bid % 588;
        int by = rem / 98, bx = rem % 98;
        int tx = tid & 31, ty = tid >> 5;
        int p0 = bx * 32, c0 = by * 32;
#pragma unroll
        for (int i = 0; i < 4; i++) {
            int c = c0 + ty + 8 * i;
            tile[ty + 8 * i][tx] = x[(b * CC + c) * HWW + p0 + tx];
        }
        __syncthreads();
#pragma unroll
        for (int i = 0; i < 4; i++) {
            int p = p0 + ty + 8 * i;
            xt[(size_t)(b * HWW + p) * CC + c0 + tx] = tile[tx][ty + 8 * i];
        }
    } else {
        int i = (bid - 2352) * 256 + tid;     // 288*256 = 73728 = 384*192
        if (i < 384 * 192) {
            int n = i / 192, k = i % 192;
            float v = (n < 192) ? cw[n * 384 + k] : cw[(n - 192) * 384 + 192 + k];
            unsigned short hi = f2b(v);
            cwh[i] = hi;
            cwl[i] = f2b(v - b2f(hi));
        }
    }
}

// ---------------------------------------------------------------------------
// Kernel 2 (R11-identical): blocks [0,1792): scores -> sp [half][b][pix][32]
//   blocks [1792,2968): GEMM [u|z] = W'·x^T, M=12544, N=384, K=192, split-bf16
// ---------------------------------------------------------------------------
__global__ __launch_bounds__(256) void k_mid(const float* __restrict__ xt,
                                             const unsigned short* __restrict__ cwh,
                                             const unsigned short* __restrict__ cwl,
                                             float* __restrict__ sp,
                                             float* __restrict__ u,
                                             float* __restrict__ z) {
    __shared__ __align__(16) char smem[36864];
    int tid = threadIdx.x, bid = blockIdx.x;

    if (bid < 1792) {                 // ---------------- scores ----------------
        float* Xs = (float*)smem;     // 28 rows x 96ch (+4 pad)
        const float K2 = 0.38490017945975050f;  // 2/sqrt(27)
        bool isH = bid < 896;
        int lid = isH ? bid : bid - 896;
        int half = lid & 1;
        int rp = (lid >> 1) & 1;
        int cb2 = lid >> 2;
        int b = cb2 / 56, l0 = cb2 % 56;
        int r0 = rp * 2;

        const float* src = xt + (size_t)(b * HWW) * CC + half * 96;
        for (int idx = tid; idx < 28 * 24; idx += 256) {
            int t2 = idx / 24, cq = idx % 24;
            int pi = (r0 + t2 / 14) + 4 * (t2 % 14);
            int pix = isH ? (pi * WW + l0) : (l0 * WW + pi);
            float4 v = *(const float4*)(src + (size_t)pix * CC + cq * 4);
            *(float4*)&Xs[t2 * 100 + cq * 4] = v;
        }
        __syncthreads();

        int perCls = isH ? 105 : 91;
        if (tid < 2 * perCls) {
            int cls = tid / perCls, p = tid % perCls;
            int a, bb;
            if (isH) {
                a = (int)((sqrtf((float)(8 * p + 1)) - 1.0f) * 0.5f);
                bb = p - (a * (a + 1)) / 2;
            } else {
                int ap = (int)((sqrtf((float)(8 * p + 1)) - 1.0f) * 0.5f);
                bb = p - (ap * (ap + 1)) / 2;
                a = ap + 1;
            }
            const float* pA = &Xs[(cls * 14 + a) * 100];
            const float* pB = &Xs[(cls * 14 + bb) * 100];
            float s0 = 0.f, s1 = 0.f, s2 = 0.f, s3 = 0.f;
#pragma unroll
            for (int q = 0; q < 24; q++) {
                float4 av = *(const float4*)(pA + q * 4);
                float4 bv = *(const float4*)(pB + q * 4);
                s0 += __builtin_amdgcn_rcpf(__expf(av.x * bv.x * K2) + 1.0f);
                s1 += __builtin_amdgcn_rcpf(__expf(av.y * bv.y * K2) + 1.0f);
                s2 += __builtin_amdgcn_rcpf(__expf(av.z * bv.z * K2) + 1.0f);
                s3 += __builtin_amdgcn_rcpf(__expf(av.w * bv.w * K2) + 1.0f);
            }
            float s = 96.0f - 2.0f * (s0 + s1 + s2 + s3);   // sum_c tanh
            int r = r0 + cls;
            size_t base = (size_t)(half * BB + b) * HWW;
            if (isH) {
                int i1 = a - bb;
                int h1 = r + 4 * a, h2 = r + 4 * bb;
                sp[(base + h1 * WW + l0) * 32 + i1] = s;
                if (a != bb) sp[(base + h2 * WW + l0) * 32 + (14 - i1)] = s;
            } else {
                int d = a - bb;                        // 1..13
                int w1 = r + 4 * a, w2 = r + 4 * bb;
                sp[(base + l0 * WW + w1) * 32 + 14 + (d - 1)] = s;
                sp[(base + l0 * WW + w2) * 32 + 14 + (13 - d)] = s;
            }
        }
        return;
    }

    // ---------------- GEMM [u|z], split-bf16, tile 64x64, K=192 ----------------
    {
        unsigned short* Ah = (unsigned short*)smem;
        unsigned short* Al = Ah + 64 * 72;
        unsigned short* Bh = Ah + 2 * 64 * 72;
        unsigned short* Bl = Ah + 3 * 64 * 72;
        float* Ds = (float*)smem;
        int vb = bid - 1792;                  // 0..1175
        int bm = (vb % 196) * 64, bn = (vb / 196) * 64;
        int lane = tid & 63, wv = tid >> 6;

        f32x4 acc[4] = {{0,0,0,0},{0,0,0,0},{0,0,0,0},{0,0,0,0}};

        for (int kc = 0; kc < 3; kc++) {
#pragma unroll
            for (int r2 = 0; r2 < 2; r2++) {
                int idx = tid + r2 * 256;
                int m = idx >> 3, kq = idx & 7;
                const float* s = xt + (size_t)(bm + m) * CC + kc * 64 + kq * 8;
                float4 v0 = *(const float4*)s;
                float4 v1 = *(const float4*)(s + 4);
                float vv[8] = {v0.x, v0.y, v0.z, v0.w, v1.x, v1.y, v1.z, v1.w};
                unsigned short hi[8], lo[8];
#pragma unroll
                for (int e = 0; e < 8; e++) {
                    hi[e] = f2b(vv[e]);
                    lo[e] = f2b(vv[e] - b2f(hi[e]));
                }
                *(short8*)&Ah[m * 72 + kq * 8] = *(short8*)hi;
                *(short8*)&Al[m * 72 + kq * 8] = *(short8*)lo;
                size_t bo = (size_t)(bn + m) * 192 + kc * 64 + kq * 8;
                *(short8*)&Bh[m * 72 + kq * 8] = *(const short8*)(cwh + bo);
                *(short8*)&Bl[m * 72 + kq * 8] = *(const short8*)(cwl + bo);
            }
            __syncthreads();
            int n0 = wv * 16;
            int k8 = lane >> 4;
            int col = lane & 15;
#pragma unroll
            for (int ks = 0; ks < 64; ks += 32) {
                int koff = ks + k8 * 8;
                short8 bfh = *(const short8*)&Bh[(n0 + col) * 72 + koff];
                short8 bfl = *(const short8*)&Bl[(n0 + col) * 72 + koff];
#pragma unroll
                for (int fm = 0; fm < 4; fm++) {
                    short8 afh = *(const short8*)&Ah[(fm * 16 + col) * 72 + koff];
                    short8 afl = *(const short8*)&Al[(fm * 16 + col) * 72 + koff];
                    acc[fm] = __builtin_amdgcn_mfma_f32_16x16x32_bf16(afh, bfh, acc[fm], 0, 0, 0);
                    acc[fm] = __builtin_amdgcn_mfma_f32_16x16x32_bf16(afl, bfh, acc[fm], 0, 0, 0);
                    acc[fm] = __builtin_amdgcn_mfma_f32_16x16x32_bf16(afh, bfl, acc[fm], 0, 0, 0);
                }
            }
            __syncthreads();
        }
        {
            int col = lane & 15, rowq = lane >> 4;
#pragma unroll
            for (int fm = 0; fm < 4; fm++)
#pragma unroll
                for (int rg = 0; rg < 4; rg++)
                    Ds[(fm * 16 + rowq * 4 + rg) * 68 + wv * 16 + col] = acc[fm][rg];
        }
        __syncthreads();
        {
            int c4 = tid & 15, m0 = tid >> 4;
            int cg = bn + c4 * 4;
            float* dst = (cg < 192) ? u : z;
            int cc = (cg < 192) ? cg : cg - 192;
#pragma unroll
            for (int p = 0; p < 4; p++) {
                int m = m0 + p * 16;
                float4 v = *(float4*)&Ds[m * 68 + c4 * 4];
                *(float4*)&dst[(size_t)(bm + m) * CC + cc] = v;
            }
        }
    }
}

// ---------------------------------------------------------------------------
// Kernel 3 finale compute body: output columns w = r + 4*(AOFF + aa), aa<7,
// all statically indexed (AOFF is a template constant; dispatch per block).
// ---------------------------------------------------------------------------
template <int AOFF>
__device__ __forceinline__ void fin_body(int b, int h, int r, int q,
                                         const float* __restrict__ u,
                                         const float* __restrict__ z,
                                         const float* __restrict__ Wt,
                                         float* __restrict__ Ys,
                                         const float* __restrict__ cb,
                                         const float* __restrict__ gma,
                                         const float* __restrict__ bta,
                                         const float* __restrict__ mea,
                                         const float* __restrict__ var) {
    int cq = q * 4;
    // own z row (full 14: W-sum needs the whole residue class)
    float4 inW[14];
#pragma unroll
    for (int t = 0; t < 14; t++)
        inW[t] = *(const float4*)(z + (size_t)(b * HWW + h * WW + (r + 4 * t)) * CC + cq);
    float4 acc[7];
#pragma unroll
    for (int aa = 0; aa < 7; aa++)
        acc[aa] = *(const float4*)(u + (size_t)(b * HWW + h * WW + (r + 4 * (AOFF + aa))) * CC + cq);
    // W-sum
#pragma unroll
    for (int j = 0; j < 13; j++)
#pragma unroll
        for (int aa = 0; aa < 7; aa++)
            fma4(acc[aa], Wt[(14 + j) * 56 + (r + 4 * (AOFF + aa))],
                 inW[(AOFF + aa - j - 1 + 14) % 14]);
    // H-sum i=0 (own row)
#pragma unroll
    for (int aa = 0; aa < 7; aa++)
        fma4(acc[aa], Wt[0 * 56 + (r + 4 * (AOFF + aa))], inW[AOFF + aa]);
    // H-sum i=1..13
#pragma unroll 1
    for (int i = 1; i < 14; i++) {
        int h2 = h - 4 * i; if (h2 < 0) h2 += 56;
        const float* zr = z + (size_t)(b * HWW + h2 * WW) * CC + cq;
#pragma unroll
        for (int aa = 0; aa < 7; aa++) {
            float4 v = *(const float4*)(zr + (size_t)(r + 4 * (AOFF + aa)) * CC);
            fma4(acc[aa], Wt[i * 56 + (r + 4 * (AOFF + aa))], v);
        }
    }
    // BN + GELU, stage to Ys[local w][c]
    float4 bias4 = *(const float4*)&cb[cq];
    float4 g4 = *(const float4*)&gma[cq];
    float4 bt4 = *(const float4*)&bta[cq];
    float4 me4 = *(const float4*)&mea[cq];
    float4 va4 = *(const float4*)&var[cq];
    float inv0 = g4.x * rsqrtf(va4.x + 1e-5f);
    float inv1 = g4.y * rsqrtf(va4.y + 1e-5f);
    float inv2 = g4.z * rsqrtf(va4.z + 1e-5f);
    float inv3 = g4.w * rsqrtf(va4.w + 1e-5f);
#pragma unroll
    for (int aa = 0; aa < 7; aa++) {
        int wl = r + 4 * aa;             // local w within the 28-column half
        float4 t = acc[aa];
        t.x = (t.x + bias4.x - me4.x) * inv0 + bt4.x;
        t.y = (t.y + bias4.y - me4.y) * inv1 + bt4.y;
        t.z = (t.z + bias4.z - me4.z) * inv2 + bt4.z;
        t.w = (t.w + bias4.w - me4.w) * inv3 + bt4.w;
        t.x = 0.5f * t.x * (1.0f + erff(t.x * 0.70710678118654752f));
        t.y = 0.5f * t.y * (1.0f + erff(t.y * 0.70710678118654752f));
        t.z = 0.5f * t.z * (1.0f + erff(t.z * 0.70710678118654752f));
        t.w = 0.5f * t.w * (1.0f + erff(t.w * 0.70710678118654752f));
        *(float4*)&Ys[wl * 196 + cq] = t;
    }
}

// ---------------------------------------------------------------------------
// Kernel 3: finale, w-split 2x: 448 blocks = (b,h) x a-half (block-uniform).
// Block ah computes columns w in [28*ah, 28*ah+28) for all 192 channels.
// ---------------------------------------------------------------------------
__global__ __launch_bounds__(192) void k_fin(const float* __restrict__ u,
                                             const float* __restrict__ z,
                                             const float* __restrict__ sp,
                                             const float* __restrict__ cb,
                                             const float* __restrict__ gma,
                                             const float* __restrict__ bta,
                                             const float* __restrict__ mea,
                                             const float* __restrict__ var,
                                             float* __restrict__ y) {
    __shared__ float Wt[27 * 56];    // [s][w] (only this block's 28 w's filled)
    __shared__ float Ys[28 * 196];   // [local w][c]
    int bid = blockIdx.x, tid = threadIdx.x;
    int ah = bid & 1;                // a-half: 0 -> w<28, 1 -> w>=28
    int lid = bid >> 1;
    int b = lid / 56, h = lid % 56;

    if (tid < 28) {
        int w = ah * 28 + tid;
        int pix = h * WW + w;
        const float4* q0 = (const float4*)&sp[((size_t)(0 * BB + b) * HWW + pix) * 32];
        const float4* q1 = (const float4*)&sp[((size_t)(1 * BB + b) * HWW + pix) * 32];
        float sc[28];
#pragma unroll
        for (int j = 0; j < 7; j++) {
            float4 a = q0[j], v = q1[j];
            sc[4 * j + 0] = a.x + v.x; sc[4 * j + 1] = a.y + v.y;
            sc[4 * j + 2] = a.z + v.z; sc[4 * j + 3] = a.w + v.w;
        }
        float mx = -1e30f;
#pragma unroll
        for (int s = 0; s < 27; s++) mx = fmaxf(mx, sc[s]);
        float sum = 0.f;
#pragma unroll
        for (int s = 0; s < 27; s++) { sc[s] = __expf(sc[s] - mx); sum += sc[s]; }
        float inv = __builtin_amdgcn_rcpf(sum);
#pragma unroll
        for (int s = 0; s < 27; s++) Wt[s * 56 + w] = sc[s] * inv;
    }
    __syncthreads();
    {
        int r = tid & 3, q = tid >> 2;   // w-residue, channel quad [0,48)
        if (ah == 0)
            fin_body<0>(b, h, r, q, u, z, Wt, Ys, cb, gma, bta, mea, var);
        else
            fin_body<7>(b, h, r, q, u, z, Wt, Ys, cb, gma, bta, mea, var);
    }
    __syncthreads();
    {
        int c = tid;   // 0..191
#pragma unroll
        for (int w4l = 0; w4l < 7; w4l++) {
            float4 v;
            v.x = Ys[(w4l * 4 + 0) * 196 + c];
            v.y = Ys[(w4l * 4 + 1) * 196 + c];
            v.z = Ys[(w4l * 4 + 2) * 196 + c];
            v.w = Ys[(w4l * 4 + 3) * 196 + c];
            *(float4*)&y[(size_t)(b * CC + c) * HWW + h * WW + (ah * 7 + w4l) * 4] = v;
        }
    }
}

// ---------------------------------------------------------------------------
extern "C" void kernel_launch(void* const* d_in, const int* in_sizes, int n_in,
                              void* d_out, int out_size, void* d_ws, size_t ws_size,
                              hipStream_t stream) {
    const float* x   = (const float*)d_in[0];
    const float* cw  = (const float*)d_in[1];
    const float* cb  = (const float*)d_in[2];
    const float* gma = (const float*)d_in[3];
    const float* bta = (const float*)d_in[4];
    const float* mea = (const float*)d_in[5];
    const float* var = (const float*)d_in[6];
    float* out = (float*)d_out;

    float* ws = (float*)d_ws;
    float*          xt  = ws;                                   // 2,408,448
    float*          sp  = ws + 2408448;                         //   802,816
    float*          u   = ws + 3211264;                         // 2,408,448
    float*          z   = ws + 5619712;                         // 2,408,448
    unsigned short* cwh = (unsigned short*)(ws + 8028160);      //    73,728 us
    unsigned short* cwl = (unsigned short*)(ws + 8065024);

    k_pre<<<2640, 256, 0, stream>>>(x, cw, xt, cwh, cwl);
    k_mid<<<2968, 256, 0, stream>>>(xt, cwh, cwl, sp, u, z);
    k_fin<<<448, 192, 0, stream>>>(u, z, sp, cb, gma, bta, mea, var, out);
}